// Round 1
// baseline (554.419 us; speedup 1.0000x reference)
//
#include <hip/hip_runtime.h>
#include <hip/hip_bf16.h>

// SelfAttention (non-local block): B=8, C=512, H=W=64 -> N=4096, CQK=32.
// Pipeline (all bf16 MFMA, fp32 accumulate):
//   1. cvt weights -> bf16
//   2. transpose x [b][c][n] f32 -> xT [b][n][c] bf16   (A/B-frag friendly)
//   3. qk proj:  qb[b][m][32], kb[b][n][32] bf16  (MFMA, xT A-frags, Wq/Wk B-frags)
//   4. v proj:   vb[b][c][n] bf16                  (MFMA)
//   5. pass1:    L[b][m] = ln(sum_n exp(S[m,n])),  S via 16x16x32 MFMA (K=32 exact)
//   6. pass2:    out[c,n] = sum_m v[c,m]*exp(S[m,n]-L[m]); flash-style, P through LDS,
//                MFMA C-init = -L[m] so D = S - L directly. No max-subtraction needed:
//                |S|<~40 so exp sums stay < 1e21 in fp32.
// ws layout (72,024,064 bytes total):
//   xT 33.5MB | vb 33.5MB | qb 2MB | kb 2MB | Wvb 512KB | Wqb 32KB | Wkb 32KB | L 128KB

typedef __attribute__((ext_vector_type(8))) short s16x8;
typedef __attribute__((ext_vector_type(4))) float f32x4;

#define MFMA16(a, b, c) __builtin_amdgcn_mfma_f32_16x16x32_bf16((a), (b), (c), 0, 0, 0)

__device__ __forceinline__ ushort f2bf(float f) {
  union { float f; unsigned u; } v; v.f = f;
  unsigned r = v.u + 0x7fffu + ((v.u >> 16) & 1u);   // RNE
  return (ushort)(r >> 16);
}

// ---------------- kernel 1: weights -> bf16 ----------------
__global__ void k_cvt_w(const float* __restrict__ Wq, const float* __restrict__ Wk,
                        const float* __restrict__ Wv, ushort* __restrict__ Wqb,
                        ushort* __restrict__ Wkb, ushort* __restrict__ Wvb) {
  int i = blockIdx.x * 256 + threadIdx.x;
  if (i < 262144) Wvb[i] = f2bf(Wv[i]);
  else if (i < 278528) Wqb[i - 262144] = f2bf(Wq[i - 262144]);
  else if (i < 294912) Wkb[i - 278528] = f2bf(Wk[i - 278528]);
}

// ---------------- kernel 2: x [b][c][n] f32 -> xT [b][n][c] bf16 ----------------
__global__ __launch_bounds__(256) void k_transpose(const float* __restrict__ x,
                                                   ushort* __restrict__ xT) {
  const int b = blockIdx.z, c0 = blockIdx.y * 64, n0 = blockIdx.x * 64;
  __shared__ __align__(16) ushort T[64][68];   // pad 64->68 keeps 8B align + banks spread
  const int t = threadIdx.x, r = t >> 2, g = t & 3;
  const float* xrow = x + ((size_t)b * 512 + c0 + r) * 4096 + n0;
  for (int j = 0; j < 4; ++j) {
    float4 f = *(const float4*)(xrow + g * 4 + j * 16);
    ushort4 u; u.x = f2bf(f.x); u.y = f2bf(f.y); u.z = f2bf(f.z); u.w = f2bf(f.w);
    *(ushort4*)&T[r][g * 4 + j * 16] = u;
  }
  __syncthreads();
  ushort* orow = xT + ((size_t)b * 4096 + n0 + r) * 512 + c0;
  for (int j = 0; j < 4; ++j) {
    int cof = g * 4 + j * 16;
    ushort4 u;
    u.x = T[cof + 0][r]; u.y = T[cof + 1][r];
    u.z = T[cof + 2][r]; u.w = T[cof + 3][r];
    *(ushort4*)&orow[cof] = u;
  }
}

// ---------------- kernel 3: q/k projection ----------------
// qb[b][m][d] = sum_c Wq[d,c] x[c,m].  MFMA: A=xT (M=m,K=c), B=Wq^T (K=c,N=d).
__global__ __launch_bounds__(256) void k_qkproj(const ushort* __restrict__ xT,
                                                const ushort* __restrict__ Wqb,
                                                const ushort* __restrict__ Wkb,
                                                ushort* __restrict__ qb,
                                                ushort* __restrict__ kb) {
  const int b = blockIdx.y, mt = blockIdx.x;
  const int lane = threadIdx.x & 63, w = threadIdx.x >> 6;
  const int quad = lane >> 4, l15 = lane & 15;
  const int m = mt * 64 + w * 16;   // this wave's 16 m-rows
  f32x4 aq[2], ak[2];
  for (int dt = 0; dt < 2; ++dt) { aq[dt] = {0.f,0.f,0.f,0.f}; ak[dt] = {0.f,0.f,0.f,0.f}; }
  const ushort* xrow = xT + ((size_t)b * 4096 + m + l15) * 512;
  for (int k0 = 0; k0 < 512; k0 += 32) {
    s16x8 ax = *(const s16x8*)(xrow + k0 + quad * 8);
    for (int dt = 0; dt < 2; ++dt) {
      s16x8 bq = *(const s16x8*)(Wqb + (size_t)(dt * 16 + l15) * 512 + k0 + quad * 8);
      s16x8 bk = *(const s16x8*)(Wkb + (size_t)(dt * 16 + l15) * 512 + k0 + quad * 8);
      aq[dt] = MFMA16(ax, bq, aq[dt]);
      ak[dt] = MFMA16(ax, bk, ak[dt]);
    }
  }
  // C layout: col d = l15(+16*dt), row m = quad*4+reg
  for (int dt = 0; dt < 2; ++dt)
    for (int r = 0; r < 4; ++r) {
      size_t mi = (size_t)b * 4096 + m + quad * 4 + r;
      qb[mi * 32 + dt * 16 + l15] = f2bf(aq[dt][r]);
      kb[mi * 32 + dt * 16 + l15] = f2bf(ak[dt][r]);
    }
}

// ---------------- kernel 4: v projection ----------------
// vb[b][c][n] = sum_c' Wv[c,c'] x[c',n]. A=Wv (M=c,K=c'), B=xT rows (K=c',N=n).
__global__ __launch_bounds__(256) void k_vproj(const ushort* __restrict__ xT,
                                               const ushort* __restrict__ Wvb,
                                               ushort* __restrict__ vb) {
  const int b = blockIdx.z, c0 = blockIdx.y * 64, n0 = blockIdx.x * 128;
  const int lane = threadIdx.x & 63, w = threadIdx.x >> 6;
  const int quad = lane >> 4, l15 = lane & 15;
  const int nsub = n0 + w * 32;
  f32x4 acc[4][2];
  for (int ci = 0; ci < 4; ++ci) for (int nj = 0; nj < 2; ++nj) acc[ci][nj] = {0.f,0.f,0.f,0.f};
  for (int k0 = 0; k0 < 512; k0 += 32) {
    s16x8 a[4], bx[2];
    for (int ci = 0; ci < 4; ++ci)
      a[ci] = *(const s16x8*)(Wvb + (size_t)(c0 + ci * 16 + l15) * 512 + k0 + quad * 8);
    for (int nj = 0; nj < 2; ++nj)
      bx[nj] = *(const s16x8*)(xT + ((size_t)b * 4096 + nsub + nj * 16 + l15) * 512 + k0 + quad * 8);
    for (int ci = 0; ci < 4; ++ci)
      for (int nj = 0; nj < 2; ++nj)
        acc[ci][nj] = MFMA16(a[ci], bx[nj], acc[ci][nj]);
  }
  for (int ci = 0; ci < 4; ++ci)
    for (int nj = 0; nj < 2; ++nj)
      for (int r = 0; r < 4; ++r)
        vb[((size_t)b * 512 + c0 + ci * 16 + quad * 4 + r) * 4096 + nsub + nj * 16 + l15] =
            f2bf(acc[ci][nj][r]);
}

// ---------------- kernel 5: pass1 — L[b][m] = ln(sum_n exp(S[m,n])) ----------------
__global__ __launch_bounds__(256) void k_pass1(const ushort* __restrict__ qb,
                                               const ushort* __restrict__ kb,
                                               float* __restrict__ L) {
  const int b = blockIdx.y, mt = blockIdx.x;
  const int lane = threadIdx.x & 63, w = threadIdx.x >> 6;
  const int quad = lane >> 4, l15 = lane & 15;
  const int m = mt * 64 + w * 16;
  const ushort* qb_b = qb + (size_t)b * 4096 * 32;
  const ushort* kb_b = kb + (size_t)b * 4096 * 32;
  const s16x8 aqf = *(const s16x8*)(qb_b + (size_t)(m + l15) * 32 + quad * 8);  // K=32 full
  float ps[4] = {0.f, 0.f, 0.f, 0.f};
  const f32x4 zf = {0.f, 0.f, 0.f, 0.f};
  for (int n0 = 0; n0 < 4096; n0 += 64) {
    for (int nt = 0; nt < 4; ++nt) {
      s16x8 bk = *(const s16x8*)(kb_b + (size_t)(n0 + nt * 16 + l15) * 32 + quad * 8);
      f32x4 s = MFMA16(aqf, bk, zf);
      for (int r = 0; r < 4; ++r) ps[r] += exp2f(s[r] * 1.4426950408889634f);
    }
  }
  // reduce across the 16 lanes of each quad (they hold cols of the same rows)
  for (int off = 1; off < 16; off <<= 1)
    for (int r = 0; r < 4; ++r) ps[r] += __shfl_xor(ps[r], off, 64);
  if (l15 == 0)
    for (int r = 0; r < 4; ++r)
      L[(size_t)b * 4096 + m + quad * 4 + r] = log2f(ps[r]) * 0.69314718055994531f;
}

// ---------------- kernel 6: pass2 — out = V @ exp(S - L) ----------------
// Block: 256 thr / 4 waves. Tile: c 256 (wave w -> 64 rows) x n 64. K-loop m chunks of 64.
__global__ __launch_bounds__(256) void k_pass2(const ushort* __restrict__ qb,
                                               const ushort* __restrict__ kb,
                                               const ushort* __restrict__ vb,
                                               const float* __restrict__ L,
                                               float* __restrict__ out) {
  const int b = blockIdx.z, ct = blockIdx.y, ntb = blockIdx.x;
  const int lane = threadIdx.x & 63, w = threadIdx.x >> 6;
  const int quad = lane >> 4, l15 = lane & 15;
  const int nbase = ntb * 64;
  const int cbase = ct * 256 + w * 64;

  __shared__ __align__(16) ushort PT[2][64][72];  // [n][m] bf16, pitch 72 keeps b128 16B-aligned

  const ushort* qb_b = qb + (size_t)b * 4096 * 32;
  const ushort* kb_b = kb + (size_t)b * 4096 * 32;
  const ushort* vb_b = vb + (size_t)b * 512 * 4096;
  const float* L_b = L + (size_t)b * 4096;

  // persistent k B-frags for this block's 64 n
  s16x8 kf[4];
  for (int nt = 0; nt < 4; ++nt)
    kf[nt] = *(const s16x8*)(kb_b + (size_t)(nbase + nt * 16 + l15) * 32 + quad * 8);

  f32x4 acc[4][4];
  for (int ci = 0; ci < 4; ++ci)
    for (int nt = 0; nt < 4; ++nt) acc[ci][nt] = {0.f, 0.f, 0.f, 0.f};

  auto produceP = [&](int chunk, int buf) {
    const int m0 = chunk * 64;
    s16x8 aq = *(const s16x8*)(qb_b + (size_t)(m0 + w * 16 + l15) * 32 + quad * 8);
    float4 l4 = *(const float4*)(L_b + m0 + w * 16 + quad * 4);
    f32x4 cin; cin.x = -l4.x; cin.y = -l4.y; cin.z = -l4.z; cin.w = -l4.w;  // D = S - L[m]
    for (int nt = 0; nt < 4; ++nt) {
      f32x4 s = MFMA16(aq, kf[nt], cin);
      ushort4 u;
      u.x = f2bf(__expf(s.x)); u.y = f2bf(__expf(s.y));
      u.z = f2bf(__expf(s.z)); u.w = f2bf(__expf(s.w));
      *(ushort4*)&PT[buf][nt * 16 + l15][w * 16 + quad * 4] = u;
    }
  };

  produceP(0, 0);
  for (int chunk = 0; chunk < 64; ++chunk) {
    __syncthreads();
    if (chunk + 1 < 64) produceP(chunk + 1, (chunk + 1) & 1);
    const int m0 = chunk * 64, buf = chunk & 1;
    s16x8 pb[4][2];
    for (int nt = 0; nt < 4; ++nt)
      for (int ks = 0; ks < 2; ++ks)
        pb[nt][ks] = *(const s16x8*)&PT[buf][nt * 16 + l15][ks * 32 + quad * 8];
    for (int ci = 0; ci < 4; ++ci) {
      const ushort* vrow = vb_b + (size_t)(cbase + ci * 16 + l15) * 4096 + m0;
      s16x8 a0 = *(const s16x8*)(vrow + quad * 8);
      s16x8 a1 = *(const s16x8*)(vrow + 32 + quad * 8);
      for (int nt = 0; nt < 4; ++nt) {
        acc[ci][nt] = MFMA16(a0, pb[nt][0], acc[ci][nt]);
        acc[ci][nt] = MFMA16(a1, pb[nt][1], acc[ci][nt]);
      }
    }
  }

  float* out_b = out + (size_t)b * 512 * 4096;
  for (int ci = 0; ci < 4; ++ci)
    for (int nt = 0; nt < 4; ++nt) {
      int n = nbase + nt * 16 + l15;
      int c0 = cbase + ci * 16 + quad * 4;
      for (int r = 0; r < 4; ++r) out_b[(size_t)(c0 + r) * 4096 + n] = acc[ci][nt][r];
    }
}

// ---------------- launch ----------------
extern "C" void kernel_launch(void* const* d_in, const int* in_sizes, int n_in,
                              void* d_out, int out_size, void* d_ws, size_t ws_size,
                              hipStream_t stream) {
  const float* x  = (const float*)d_in[0];   // [8,512,64,64]
  const float* Wq = (const float*)d_in[1];   // [32,512]
  const float* Wk = (const float*)d_in[2];   // [32,512]
  const float* Wv = (const float*)d_in[3];   // [512,512]
  float* out = (float*)d_out;                // [8,512,64,64]

  char* ws = (char*)d_ws;
  ushort* xT  = (ushort*)(ws + 0);           // 33,554,432 B
  ushort* vb  = (ushort*)(ws + 33554432);    // 33,554,432 B
  ushort* qb  = (ushort*)(ws + 67108864);    //  2,097,152 B
  ushort* kb  = (ushort*)(ws + 69206016);    //  2,097,152 B
  ushort* Wvb = (ushort*)(ws + 71303168);    //    524,288 B
  ushort* Wqb = (ushort*)(ws + 71827456);    //     32,768 B
  ushort* Wkb = (ushort*)(ws + 71860224);    //     32,768 B
  float*  Lrs = (float*)(ws + 71892992);     //    131,072 B  (total 72,024,064)

  hipLaunchKernelGGL(k_cvt_w, dim3(1152), dim3(256), 0, stream, Wq, Wk, Wv, Wqb, Wkb, Wvb);
  hipLaunchKernelGGL(k_transpose, dim3(64, 8, 8), dim3(256), 0, stream, x, xT);
  hipLaunchKernelGGL(k_qkproj, dim3(64, 8), dim3(256), 0, stream, xT, Wqb, Wkb, qb, kb);
  hipLaunchKernelGGL(k_vproj, dim3(32, 8, 8), dim3(256), 0, stream, xT, Wvb, vb);
  hipLaunchKernelGGL(k_pass1, dim3(64, 8), dim3(256), 0, stream, qb, kb, Lrs);
  hipLaunchKernelGGL(k_pass2, dim3(64, 2, 8), dim3(256), 0, stream, qb, kb, vb, Lrs, out);
}